// Round 2
// baseline (642.473 us; speedup 1.0000x reference)
//
#include <hip/hip_runtime.h>
#include <hip/hip_fp16.h>

// MultiScaleDeformableAttention forward (Deformable-DETR), fp32 in/out.
// B=4, S=21760, H=8, D=32, Q=10000, L=4, P=4.
// Levels (static): (128,128),(64,64),(32,32),(16,16); starts 0,16384,20480,21504.
//
// Round 7 (round-6 never benched: broker timeouts). Design: prior profile
// showed a per-CU VMEM random-gather request wall (~206-212us, insensitive to
// occupancy 25-60%). Levels 2+3 are 80KB/(b,h) contiguous in fp16 [B,H,S,D];
// stage them in LDS and service 50% of corner-gathers from the LDS pipe.
// Round-7 fix vs round-6: 512-thread blocks (was 256). LDS caps us at
// 2 blocks/CU; 256-thread blocks left only 2 waves/SIMD (below the measured
// occupancy-insensitive band -> latency-bind risk on the remaining L0/L1
// gathers). 512 threads -> 4 waves/SIMD at the same 80KB LDS.
// __launch_bounds__(512,4) pins VGPR<=128 so the 2-block fit is guaranteed.
// Fallbacks: no big-LDS attr -> round-5 fp16 kernel; small ws -> fp32 kernel.

#define MSDA_B 4
#define MSDA_Q 10000
#define MSDA_H 8
#define MSDA_D 32
#define MSDA_L 4
#define MSDA_P 4
#define MSDA_S 21760

#define MSDA_QBLK16 157   // ceil(10000/64) q-blocks per (b,h) (round-5 fp16 path)
#define MSDA_QBLK32 313   // ceil(10000/32) (fp32 fallback path)

#define MSDA_NB 16        // q-chunks per (b,h) slice (LDS path)
#define MSDA_QPC 640      // queries per chunk = 5 iters * 128
#define MSDA_LDS_BYTES 81920  // levels 2+3: 1280 pixels * 64 B

// ---------------- pre-pass: fp32 [B,S,H,D] -> fp16 [B,H,S,D] ----------------
__global__ __launch_bounds__(256) void msda_convert_kernel(
    const float* __restrict__ value, __half* __restrict__ vw)
{
    int o4 = blockIdx.x * 256 + threadIdx.x;      // index of 4 halves in output
    int d4 = o4 & 7;                               // D/4 = 8
    int rest = o4 >> 3;                            // (b*H + h)*S + s
    int s = rest % MSDA_S;
    int bh = rest / MSDA_S;
    int b = bh >> 3, h = bh & 7;
    float4 v = *(const float4*)(value +
        (((size_t)b * MSDA_S + s) * MSDA_H + h) * MSDA_D + 4 * d4);
    union { __half2 h2[2]; uint2 u; } pk;
    pk.h2[0] = __floats2half2_rn(v.x, v.y);
    pk.h2[1] = __floats2half2_rn(v.z, v.w);
    ((uint2*)vw)[o4] = pk.u;
}

// ---------------- main kernel (fp16 gather + LDS levels 2,3) ----------------
__global__ __launch_bounds__(512, 4) void msda_fwd_lds_kernel(
    const __half* __restrict__ vw,     // [B,H,S,D] fp16
    const float* __restrict__ loc,     // [B,Q,H,L,P,2]
    const float* __restrict__ aw,      // [B,Q,H,L,P]
    float* __restrict__ out)           // [B,Q,H,D]
{
    constexpr int H = MSDA_H, D = MSDA_D, L = MSDA_L, P = MSDA_P;
    constexpr int Q = MSDA_Q, S = MSDA_S;
    const int lvl_sh[4]    = {7, 6, 5, 4};
    const int lvl_start[4] = {0, 16384, 20480, 21504};
    const int lvl_lstart[4] = {0, 0, 0, 1024};   // local pixel base in LDS (l>=2)

    extern __shared__ char smem[];

    // XCD-affine: blockIdx%8 = XCD = head
    int i = blockIdx.x;
    int h = i & 7;
    int r = i >> 3;
    int qc = r & (MSDA_NB - 1);
    int b = r >> 4;

    const size_t slice = (size_t)(b * H + h) * S * D;   // in halves

    // ---- stage levels 2+3 (pixels 20480..21759, 80KB contiguous) ----
    {
        const uint4* src = (const uint4*)(vw + slice + (size_t)20480 * D);
        uint4* dst = (uint4*)smem;
#pragma unroll
        for (int k = 0; k < 10; ++k)
            dst[threadIdx.x + 512 * k] = src[threadIdx.x + 512 * k];
    }
    __syncthreads();

    const int lane = threadIdx.x & 3;
    const unsigned coff = (unsigned)lane * 16;    // 16B = 8 halves = d[8k..8k+7]
    const int qsub = threadIdx.x >> 2;            // 4 lanes per (b,q,h); 128 quads
    const char* vb = (const char*)(vw + slice);

    for (int it = 0; it < MSDA_QPC / 128; ++it) {
        int q = qc * MSDA_QPC + it * 128 + qsub;
        if (q >= Q) break;                        // monotone in it; no barriers below

        const size_t bqh = ((size_t)b * Q + q) * H + h;
        const float4* lp4 = (const float4*)(loc + bqh * (L * P * 2));
        const float4* wp4 = (const float4*)(aw  + bqh * (L * P));

        float2 acc[4] = {{0.f,0.f},{0.f,0.f},{0.f,0.f},{0.f,0.f}};

#pragma unroll
        for (int l = 0; l < L; ++l) {
            const int sh = lvl_sh[l];
            const int hw = 1 << sh;
            const float fhw = (float)hw;

            float4 la = lp4[2 * l + 0];
            float4 lb = lp4[2 * l + 1];
            float4 wv = wp4[l];
            float lx[4] = {la.x, la.z, lb.x, lb.z};
            float ly[4] = {la.y, la.w, lb.y, lb.w};
            float wl[4] = {wv.x, wv.y, wv.z, wv.w};

#pragma unroll
            for (int p = 0; p < P; ++p) {
                float x = lx[p] * fhw - 0.5f;
                float y = ly[p] * fhw - 0.5f;
                float xf = floorf(x), yf = floorf(y);
                float fx = x - xf, fy = y - yf;
                int x0 = (int)xf, y0 = (int)yf;
                int x1 = x0 + 1, y1 = y0 + 1;

                float vx0 = ((unsigned)x0 < (unsigned)hw) ? 1.f : 0.f;
                float vx1 = ((unsigned)x1 < (unsigned)hw) ? 1.f : 0.f;
                float vy0 = ((unsigned)y0 < (unsigned)hw) ? 1.f : 0.f;
                float vy1 = ((unsigned)y1 < (unsigned)hw) ? 1.f : 0.f;

                int cx0 = min(max(x0, 0), hw - 1);
                int cx1 = min(max(x1, 0), hw - 1);
                int cy0 = min(max(y0, 0), hw - 1);
                int cy1 = min(max(y1, 0), hw - 1);

                int r0 = cy0 << sh;
                int r1 = cy1 << sh;

                union U { uint4 u; __half2 h2[4]; };
                U u00, u01, u10, u11;

                if (l < 2) {
                    // global fp16 gather (pixel = 64 B)
                    const int start = lvl_start[l];
                    unsigned o00 = ((unsigned)(start + r0 + cx0) << 6) + coff;
                    unsigned o01 = ((unsigned)(start + r0 + cx1) << 6) + coff;
                    unsigned o10 = ((unsigned)(start + r1 + cx0) << 6) + coff;
                    unsigned o11 = ((unsigned)(start + r1 + cx1) << 6) + coff;
                    u00.u = *(const uint4*)(vb + o00);
                    u01.u = *(const uint4*)(vb + o01);
                    u10.u = *(const uint4*)(vb + o10);
                    u11.u = *(const uint4*)(vb + o11);
                } else {
                    // LDS gather (levels 2,3 staged; 64B-aligned bases)
                    const int lstart = lvl_lstart[l];
                    unsigned o00 = ((unsigned)(lstart + r0 + cx0) << 6) + coff;
                    unsigned o01 = ((unsigned)(lstart + r0 + cx1) << 6) + coff;
                    unsigned o10 = ((unsigned)(lstart + r1 + cx0) << 6) + coff;
                    unsigned o11 = ((unsigned)(lstart + r1 + cx1) << 6) + coff;
                    u00.u = *(const uint4*)(smem + o00);
                    u01.u = *(const uint4*)(smem + o01);
                    u10.u = *(const uint4*)(smem + o10);
                    u11.u = *(const uint4*)(smem + o11);
                }

                float wgt = wl[p];
                float w00 = (1.f - fx) * (1.f - fy) * wgt * vx0 * vy0;
                float w01 = fx * (1.f - fy) * wgt * vx1 * vy0;
                float w10 = (1.f - fx) * fy * wgt * vx0 * vy1;
                float w11 = fx * fy * wgt * vx1 * vy1;

#pragma unroll
                for (int j = 0; j < 4; ++j) {
                    float2 f00 = __half22float2(u00.h2[j]);
                    float2 f01 = __half22float2(u01.h2[j]);
                    float2 f10 = __half22float2(u10.h2[j]);
                    float2 f11 = __half22float2(u11.h2[j]);
                    acc[j].x += w00 * f00.x + w01 * f01.x + w10 * f10.x + w11 * f11.x;
                    acc[j].y += w00 * f00.y + w01 * f01.y + w10 * f10.y + w11 * f11.y;
                }
            }
        }

        // lane owns d[8*lane .. 8*lane+7] -> float4 chunks 2*lane, 2*lane+1
        float4* op = (float4*)out + bqh * (D / 4) + lane * 2;
        op[0] = make_float4(acc[0].x, acc[0].y, acc[1].x, acc[1].y);
        op[1] = make_float4(acc[2].x, acc[2].y, acc[3].x, acc[3].y);
    }
}

// ---------------- round-5 fp16 kernel (fallback if big-LDS attr fails) ------
__global__ __launch_bounds__(256) void msda_fwd_fp16_kernel(
    const __half* __restrict__ vw, const float* __restrict__ loc,
    const float* __restrict__ aw, float* __restrict__ out)
{
    constexpr int H = MSDA_H, D = MSDA_D, L = MSDA_L, P = MSDA_P;
    constexpr int S = MSDA_S, Q = MSDA_Q;
    const int lvl_sh[4]    = {7, 6, 5, 4};
    const int lvl_start[4] = {0, 16384, 20480, 21504};

    int i = blockIdx.x;
    int h = i & 7;
    int r = i >> 3;
    int b = r / MSDA_QBLK16;
    int qb = r - b * MSDA_QBLK16;

    int q = qb * 64 + (threadIdx.x >> 2);
    if (q >= Q) return;
    const int lane = threadIdx.x & 3;
    const unsigned coff = (unsigned)lane * 16;

    const size_t bqh = ((size_t)b * Q + q) * H + h;
    const float4* lp4 = (const float4*)(loc + bqh * (L * P * 2));
    const float4* wp4 = (const float4*)(aw  + bqh * (L * P));
    const char* vb = (const char*)(vw + (size_t)(b * H + h) * S * D);

    float2 acc[4] = {{0.f,0.f},{0.f,0.f},{0.f,0.f},{0.f,0.f}};

#pragma unroll
    for (int l = 0; l < L; ++l) {
        const int sh = lvl_sh[l];
        const int hw = 1 << sh;
        const float fhw = (float)hw;
        const int start = lvl_start[l];

        float4 la = lp4[2 * l + 0];
        float4 lb = lp4[2 * l + 1];
        float4 wv = wp4[l];
        float lx[4] = {la.x, la.z, lb.x, lb.z};
        float ly[4] = {la.y, la.w, lb.y, lb.w};
        float wl[4] = {wv.x, wv.y, wv.z, wv.w};

#pragma unroll
        for (int p = 0; p < P; ++p) {
            float x = lx[p] * fhw - 0.5f;
            float y = ly[p] * fhw - 0.5f;
            float xf = floorf(x), yf = floorf(y);
            float fx = x - xf, fy = y - yf;
            int x0 = (int)xf, y0 = (int)yf;
            int x1 = x0 + 1, y1 = y0 + 1;

            float vx0 = ((unsigned)x0 < (unsigned)hw) ? 1.f : 0.f;
            float vx1 = ((unsigned)x1 < (unsigned)hw) ? 1.f : 0.f;
            float vy0 = ((unsigned)y0 < (unsigned)hw) ? 1.f : 0.f;
            float vy1 = ((unsigned)y1 < (unsigned)hw) ? 1.f : 0.f;

            int cx0 = min(max(x0, 0), hw - 1);
            int cx1 = min(max(x1, 0), hw - 1);
            int cy0 = min(max(y0, 0), hw - 1);
            int cy1 = min(max(y1, 0), hw - 1);

            int r0 = start + (cy0 << sh);
            int r1 = start + (cy1 << sh);
            unsigned o00 = ((unsigned)(r0 + cx0) << 6) + coff;
            unsigned o01 = ((unsigned)(r0 + cx1) << 6) + coff;
            unsigned o10 = ((unsigned)(r1 + cx0) << 6) + coff;
            unsigned o11 = ((unsigned)(r1 + cx1) << 6) + coff;

            union U { uint4 u; __half2 h2[4]; };
            U u00, u01, u10, u11;
            u00.u = *(const uint4*)(vb + o00);
            u01.u = *(const uint4*)(vb + o01);
            u10.u = *(const uint4*)(vb + o10);
            u11.u = *(const uint4*)(vb + o11);

            float wgt = wl[p];
            float w00 = (1.f - fx) * (1.f - fy) * wgt * vx0 * vy0;
            float w01 = fx * (1.f - fy) * wgt * vx1 * vy0;
            float w10 = (1.f - fx) * fy * wgt * vx0 * vy1;
            float w11 = fx * fy * wgt * vx1 * vy1;

#pragma unroll
            for (int j = 0; j < 4; ++j) {
                float2 f00 = __half22float2(u00.h2[j]);
                float2 f01 = __half22float2(u01.h2[j]);
                float2 f10 = __half22float2(u10.h2[j]);
                float2 f11 = __half22float2(u11.h2[j]);
                acc[j].x += w00 * f00.x + w01 * f01.x + w10 * f10.x + w11 * f11.x;
                acc[j].y += w00 * f00.y + w01 * f01.y + w10 * f10.y + w11 * f11.y;
            }
        }
    }

    float4* op = (float4*)out + bqh * (D / 4) + lane * 2;
    op[0] = make_float4(acc[0].x, acc[0].y, acc[1].x, acc[1].y);
    op[1] = make_float4(acc[2].x, acc[2].y, acc[3].x, acc[3].y);
}

// ---------------- fp32 fallback (round-4 kernel) ----------------
__global__ __launch_bounds__(256, 4) void msda_fwd_fp32_kernel(
    const float* __restrict__ value, const float* __restrict__ loc,
    const float* __restrict__ aw, float* __restrict__ out)
{
    constexpr int H = MSDA_H, D = MSDA_D, L = MSDA_L, P = MSDA_P;
    constexpr int S = MSDA_S, Q = MSDA_Q;
    const int lvl_sh[4]    = {7, 6, 5, 4};
    const int lvl_start[4] = {0, 16384, 20480, 21504};

    int i = blockIdx.x;
    int h = i & 7;
    int r = i >> 3;
    int b = r / MSDA_QBLK32;
    int qb = r - b * MSDA_QBLK32;

    int q = qb * 32 + (threadIdx.x >> 3);
    if (q >= Q) return;
    const unsigned coff = (threadIdx.x & 7) * 16;

    const size_t bqh = ((size_t)b * Q + q) * H + h;
    const float4* lp4 = (const float4*)(loc + bqh * (L * P * 2));
    const float4* wp4 = (const float4*)(aw  + bqh * (L * P));
    const char* vb = (const char*)(value + ((size_t)b * S * H + h) * D);

    float4 acc = {0.f, 0.f, 0.f, 0.f};

#pragma unroll
    for (int l = 0; l < L; ++l) {
        const int sh = lvl_sh[l];
        const int hw = 1 << sh;
        const float fhw = (float)hw;
        const int start = lvl_start[l];

        float4 la = lp4[2 * l + 0];
        float4 lb = lp4[2 * l + 1];
        float4 wv = wp4[l];
        float lx[4] = {la.x, la.z, lb.x, lb.z};
        float ly[4] = {la.y, la.w, lb.y, lb.w};
        float wl[4] = {wv.x, wv.y, wv.z, wv.w};

#pragma unroll
        for (int p = 0; p < P; ++p) {
            float x = lx[p] * fhw - 0.5f;
            float y = ly[p] * fhw - 0.5f;
            float xf = floorf(x), yf = floorf(y);
            float fx = x - xf, fy = y - yf;
            int x0 = (int)xf, y0 = (int)yf;
            int x1 = x0 + 1, y1 = y0 + 1;

            float vx0 = ((unsigned)x0 < (unsigned)hw) ? 1.f : 0.f;
            float vx1 = ((unsigned)x1 < (unsigned)hw) ? 1.f : 0.f;
            float vy0 = ((unsigned)y0 < (unsigned)hw) ? 1.f : 0.f;
            float vy1 = ((unsigned)y1 < (unsigned)hw) ? 1.f : 0.f;

            int cx0 = min(max(x0, 0), hw - 1);
            int cx1 = min(max(x1, 0), hw - 1);
            int cy0 = min(max(y0, 0), hw - 1);
            int cy1 = min(max(y1, 0), hw - 1);

            float wgt = wl[p];
            float w00 = (1.f - fx) * (1.f - fy) * wgt * vx0 * vy0;
            float w01 = fx * (1.f - fy) * wgt * vx1 * vy0;
            float w10 = (1.f - fx) * fy * wgt * vx0 * vy1;
            float w11 = fx * fy * wgt * vx1 * vy1;

            int r0 = start + (cy0 << sh);
            int r1 = start + (cy1 << sh);
            unsigned o00 = ((unsigned)(r0 + cx0) << 10) + coff;
            unsigned o01 = ((unsigned)(r0 + cx1) << 10) + coff;
            unsigned o10 = ((unsigned)(r1 + cx0) << 10) + coff;
            unsigned o11 = ((unsigned)(r1 + cx1) << 10) + coff;

            float4 v00 = *(const float4*)(vb + o00);
            float4 v01 = *(const float4*)(vb + o01);
            float4 v10 = *(const float4*)(vb + o10);
            float4 v11 = *(const float4*)(vb + o11);

            acc.x += w00 * v00.x + w01 * v01.x + w10 * v10.x + w11 * v11.x;
            acc.y += w00 * v00.y + w01 * v01.y + w10 * v10.y + w11 * v11.y;
            acc.z += w00 * v00.z + w01 * v01.z + w10 * v10.z + w11 * v11.z;
            acc.w += w00 * v00.w + w01 * v01.w + w10 * v10.w + w11 * v11.w;
        }
    }

    ((float4*)out)[bqh * (D / 4) + (threadIdx.x & 7)] = acc;
}

extern "C" void kernel_launch(void* const* d_in, const int* in_sizes, int n_in,
                              void* d_out, int out_size, void* d_ws, size_t ws_size,
                              hipStream_t stream) {
    const float* value = (const float*)d_in[0];
    const float* loc = (const float*)d_in[3];
    const float* aw  = (const float*)d_in[4];
    float* out = (float*)d_out;

    // one-time: allow 80KB dynamic LDS on the LDS-path kernel
    static int lds_ok = -1;
    if (lds_ok < 0) {
        hipError_t e = hipFuncSetAttribute(
            reinterpret_cast<const void*>(msda_fwd_lds_kernel),
            hipFuncAttributeMaxDynamicSharedMemorySize, MSDA_LDS_BYTES);
        lds_ok = (e == hipSuccess) ? 1 : 0;
    }

    const size_t need = (size_t)MSDA_B * MSDA_H * MSDA_S * MSDA_D * sizeof(__half);
    if (ws_size >= need) {
        __half* vw = (__half*)d_ws;
        msda_convert_kernel<<<(MSDA_B * MSDA_S * MSDA_H * MSDA_D / 4 + 255) / 256,
                              256, 0, stream>>>(value, vw);
        if (lds_ok) {
            const int grid = MSDA_B * MSDA_H * MSDA_NB;   // 512
            msda_fwd_lds_kernel<<<grid, 512, MSDA_LDS_BYTES, stream>>>(vw, loc, aw, out);
        } else {
            const int grid = 8 * MSDA_B * MSDA_QBLK16;    // 5024
            msda_fwd_fp16_kernel<<<grid, 256, 0, stream>>>(vw, loc, aw, out);
        }
    } else {
        const int grid = 8 * MSDA_B * MSDA_QBLK32;        // 10016
        msda_fwd_fp32_kernel<<<grid, 256, 0, stream>>>(value, loc, aw, out);
    }
}

// Round 3
// 275.935 us; speedup vs baseline: 2.3284x; 2.3284x over previous
//
#include <hip/hip_runtime.h>
#include <hip/hip_fp16.h>

// MultiScaleDeformableAttention forward (Deformable-DETR), fp32 in/out.
// B=4, S=21760, H=8, D=32, Q=10000, L=4, P=4.
// Levels (static): (128,128),(64,64),(32,32),(16,16); starts 0,16384,20480,21504.
//
// Round 8. Round-7 post-mortem (first real counters this session):
//   __launch_bounds__(512,4) was interpreted as 4 BLOCKS/CU (CUDA semantics)
//   -> VGPR capped at 64 (measured VGPR_Count=64) -> scratch spills ->
//   FETCH 0.87 GB + WRITE 1.0 GB of spill traffic -> HBM-bound 493us
//   (3.9 TB/s, VALUBusy 10.6%). LDS design itself validated: bank-conflict
//   cost ~4.6us/CU aggregate (2.86M cycles), occupancy 41% (16 waves/CU).
// Fix: __launch_bounds__(512, 2) -> VGPR cap >=128 under either semantics;
//   compiler needs ~90 -> no spill; LDS (80KB) still allows 2 blocks/CU.
// Design recap: levels 2+3 (80KB/(b,h), contiguous fp16) staged in LDS;
//   50% of corner-gathers served by the LDS pipe; levels 0+1 gather fp16
//   from global, XCD-affine (blockIdx%8 = head).
// Fallbacks: no big-LDS attr -> round-5 fp16 kernel; small ws -> fp32 kernel.

#define MSDA_B 4
#define MSDA_Q 10000
#define MSDA_H 8
#define MSDA_D 32
#define MSDA_L 4
#define MSDA_P 4
#define MSDA_S 21760

#define MSDA_QBLK16 157   // ceil(10000/64) q-blocks per (b,h) (round-5 fp16 path)
#define MSDA_QBLK32 313   // ceil(10000/32) (fp32 fallback path)

#define MSDA_NB 16        // q-chunks per (b,h) slice (LDS path)
#define MSDA_QPC 640      // queries per chunk = 5 iters * 128
#define MSDA_LDS_BYTES 81920  // levels 2+3: 1280 pixels * 64 B

// ---------------- pre-pass: fp32 [B,S,H,D] -> fp16 [B,H,S,D] ----------------
__global__ __launch_bounds__(256) void msda_convert_kernel(
    const float* __restrict__ value, __half* __restrict__ vw)
{
    int o4 = blockIdx.x * 256 + threadIdx.x;      // index of 4 halves in output
    int d4 = o4 & 7;                               // D/4 = 8
    int rest = o4 >> 3;                            // (b*H + h)*S + s
    int s = rest % MSDA_S;
    int bh = rest / MSDA_S;
    int b = bh >> 3, h = bh & 7;
    float4 v = *(const float4*)(value +
        (((size_t)b * MSDA_S + s) * MSDA_H + h) * MSDA_D + 4 * d4);
    union { __half2 h2[2]; uint2 u; } pk;
    pk.h2[0] = __floats2half2_rn(v.x, v.y);
    pk.h2[1] = __floats2half2_rn(v.z, v.w);
    ((uint2*)vw)[o4] = pk.u;
}

// ---------------- main kernel (fp16 gather + LDS levels 2,3) ----------------
__global__ __launch_bounds__(512, 2) void msda_fwd_lds_kernel(
    const __half* __restrict__ vw,     // [B,H,S,D] fp16
    const float* __restrict__ loc,     // [B,Q,H,L,P,2]
    const float* __restrict__ aw,      // [B,Q,H,L,P]
    float* __restrict__ out)           // [B,Q,H,D]
{
    constexpr int H = MSDA_H, D = MSDA_D, L = MSDA_L, P = MSDA_P;
    constexpr int Q = MSDA_Q, S = MSDA_S;
    const int lvl_sh[4]    = {7, 6, 5, 4};
    const int lvl_start[4] = {0, 16384, 20480, 21504};
    const int lvl_lstart[4] = {0, 0, 0, 1024};   // local pixel base in LDS (l>=2)

    extern __shared__ char smem[];

    // XCD-affine: blockIdx%8 = XCD = head
    int i = blockIdx.x;
    int h = i & 7;
    int r = i >> 3;
    int qc = r & (MSDA_NB - 1);
    int b = r >> 4;

    const size_t slice = (size_t)(b * H + h) * S * D;   // in halves

    // ---- stage levels 2+3 (pixels 20480..21759, 80KB contiguous) ----
    {
        const uint4* src = (const uint4*)(vw + slice + (size_t)20480 * D);
        uint4* dst = (uint4*)smem;
#pragma unroll
        for (int k = 0; k < 10; ++k)
            dst[threadIdx.x + 512 * k] = src[threadIdx.x + 512 * k];
    }
    __syncthreads();

    const int lane = threadIdx.x & 3;
    const unsigned coff = (unsigned)lane * 16;    // 16B = 8 halves = d[8k..8k+7]
    const int qsub = threadIdx.x >> 2;            // 4 lanes per (b,q,h); 128 quads
    const char* vb = (const char*)(vw + slice);

    for (int it = 0; it < MSDA_QPC / 128; ++it) {
        int q = qc * MSDA_QPC + it * 128 + qsub;
        if (q >= Q) break;                        // monotone in it; no barriers below

        const size_t bqh = ((size_t)b * Q + q) * H + h;
        const float4* lp4 = (const float4*)(loc + bqh * (L * P * 2));
        const float4* wp4 = (const float4*)(aw  + bqh * (L * P));

        float2 acc[4] = {{0.f,0.f},{0.f,0.f},{0.f,0.f},{0.f,0.f}};

#pragma unroll
        for (int l = 0; l < L; ++l) {
            const int sh = lvl_sh[l];
            const int hw = 1 << sh;
            const float fhw = (float)hw;

            float4 la = lp4[2 * l + 0];
            float4 lb = lp4[2 * l + 1];
            float4 wv = wp4[l];
            float lx[4] = {la.x, la.z, lb.x, lb.z};
            float ly[4] = {la.y, la.w, lb.y, lb.w};
            float wl[4] = {wv.x, wv.y, wv.z, wv.w};

#pragma unroll
            for (int p = 0; p < P; ++p) {
                float x = lx[p] * fhw - 0.5f;
                float y = ly[p] * fhw - 0.5f;
                float xf = floorf(x), yf = floorf(y);
                float fx = x - xf, fy = y - yf;
                int x0 = (int)xf, y0 = (int)yf;
                int x1 = x0 + 1, y1 = y0 + 1;

                float vx0 = ((unsigned)x0 < (unsigned)hw) ? 1.f : 0.f;
                float vx1 = ((unsigned)x1 < (unsigned)hw) ? 1.f : 0.f;
                float vy0 = ((unsigned)y0 < (unsigned)hw) ? 1.f : 0.f;
                float vy1 = ((unsigned)y1 < (unsigned)hw) ? 1.f : 0.f;

                int cx0 = min(max(x0, 0), hw - 1);
                int cx1 = min(max(x1, 0), hw - 1);
                int cy0 = min(max(y0, 0), hw - 1);
                int cy1 = min(max(y1, 0), hw - 1);

                int r0 = cy0 << sh;
                int r1 = cy1 << sh;

                union U { uint4 u; __half2 h2[4]; };
                U u00, u01, u10, u11;

                if (l < 2) {
                    // global fp16 gather (pixel = 64 B)
                    const int start = lvl_start[l];
                    unsigned o00 = ((unsigned)(start + r0 + cx0) << 6) + coff;
                    unsigned o01 = ((unsigned)(start + r0 + cx1) << 6) + coff;
                    unsigned o10 = ((unsigned)(start + r1 + cx0) << 6) + coff;
                    unsigned o11 = ((unsigned)(start + r1 + cx1) << 6) + coff;
                    u00.u = *(const uint4*)(vb + o00);
                    u01.u = *(const uint4*)(vb + o01);
                    u10.u = *(const uint4*)(vb + o10);
                    u11.u = *(const uint4*)(vb + o11);
                } else {
                    // LDS gather (levels 2,3 staged; 64B-aligned bases)
                    const int lstart = lvl_lstart[l];
                    unsigned o00 = ((unsigned)(lstart + r0 + cx0) << 6) + coff;
                    unsigned o01 = ((unsigned)(lstart + r0 + cx1) << 6) + coff;
                    unsigned o10 = ((unsigned)(lstart + r1 + cx0) << 6) + coff;
                    unsigned o11 = ((unsigned)(lstart + r1 + cx1) << 6) + coff;
                    u00.u = *(const uint4*)(smem + o00);
                    u01.u = *(const uint4*)(smem + o01);
                    u10.u = *(const uint4*)(smem + o10);
                    u11.u = *(const uint4*)(smem + o11);
                }

                float wgt = wl[p];
                float w00 = (1.f - fx) * (1.f - fy) * wgt * vx0 * vy0;
                float w01 = fx * (1.f - fy) * wgt * vx1 * vy0;
                float w10 = (1.f - fx) * fy * wgt * vx0 * vy1;
                float w11 = fx * fy * wgt * vx1 * vy1;

#pragma unroll
                for (int j = 0; j < 4; ++j) {
                    float2 f00 = __half22float2(u00.h2[j]);
                    float2 f01 = __half22float2(u01.h2[j]);
                    float2 f10 = __half22float2(u10.h2[j]);
                    float2 f11 = __half22float2(u11.h2[j]);
                    acc[j].x += w00 * f00.x + w01 * f01.x + w10 * f10.x + w11 * f11.x;
                    acc[j].y += w00 * f00.y + w01 * f01.y + w10 * f10.y + w11 * f11.y;
                }
            }
        }

        // lane owns d[8*lane .. 8*lane+7] -> float4 chunks 2*lane, 2*lane+1
        float4* op = (float4*)out + bqh * (D / 4) + lane * 2;
        op[0] = make_float4(acc[0].x, acc[0].y, acc[1].x, acc[1].y);
        op[1] = make_float4(acc[2].x, acc[2].y, acc[3].x, acc[3].y);
    }
}

// ---------------- round-5 fp16 kernel (fallback if big-LDS attr fails) ------
__global__ __launch_bounds__(256) void msda_fwd_fp16_kernel(
    const __half* __restrict__ vw, const float* __restrict__ loc,
    const float* __restrict__ aw, float* __restrict__ out)
{
    constexpr int H = MSDA_H, D = MSDA_D, L = MSDA_L, P = MSDA_P;
    constexpr int S = MSDA_S, Q = MSDA_Q;
    const int lvl_sh[4]    = {7, 6, 5, 4};
    const int lvl_start[4] = {0, 16384, 20480, 21504};

    int i = blockIdx.x;
    int h = i & 7;
    int r = i >> 3;
    int b = r / MSDA_QBLK16;
    int qb = r - b * MSDA_QBLK16;

    int q = qb * 64 + (threadIdx.x >> 2);
    if (q >= Q) return;
    const int lane = threadIdx.x & 3;
    const unsigned coff = (unsigned)lane * 16;

    const size_t bqh = ((size_t)b * Q + q) * H + h;
    const float4* lp4 = (const float4*)(loc + bqh * (L * P * 2));
    const float4* wp4 = (const float4*)(aw  + bqh * (L * P));
    const char* vb = (const char*)(vw + (size_t)(b * H + h) * S * D);

    float2 acc[4] = {{0.f,0.f},{0.f,0.f},{0.f,0.f},{0.f,0.f}};

#pragma unroll
    for (int l = 0; l < L; ++l) {
        const int sh = lvl_sh[l];
        const int hw = 1 << sh;
        const float fhw = (float)hw;
        const int start = lvl_start[l];

        float4 la = lp4[2 * l + 0];
        float4 lb = lp4[2 * l + 1];
        float4 wv = wp4[l];
        float lx[4] = {la.x, la.z, lb.x, lb.z};
        float ly[4] = {la.y, la.w, lb.y, lb.w};
        float wl[4] = {wv.x, wv.y, wv.z, wv.w};

#pragma unroll
        for (int p = 0; p < P; ++p) {
            float x = lx[p] * fhw - 0.5f;
            float y = ly[p] * fhw - 0.5f;
            float xf = floorf(x), yf = floorf(y);
            float fx = x - xf, fy = y - yf;
            int x0 = (int)xf, y0 = (int)yf;
            int x1 = x0 + 1, y1 = y0 + 1;

            float vx0 = ((unsigned)x0 < (unsigned)hw) ? 1.f : 0.f;
            float vx1 = ((unsigned)x1 < (unsigned)hw) ? 1.f : 0.f;
            float vy0 = ((unsigned)y0 < (unsigned)hw) ? 1.f : 0.f;
            float vy1 = ((unsigned)y1 < (unsigned)hw) ? 1.f : 0.f;

            int cx0 = min(max(x0, 0), hw - 1);
            int cx1 = min(max(x1, 0), hw - 1);
            int cy0 = min(max(y0, 0), hw - 1);
            int cy1 = min(max(y1, 0), hw - 1);

            int r0 = start + (cy0 << sh);
            int r1 = start + (cy1 << sh);
            unsigned o00 = ((unsigned)(r0 + cx0) << 6) + coff;
            unsigned o01 = ((unsigned)(r0 + cx1) << 6) + coff;
            unsigned o10 = ((unsigned)(r1 + cx0) << 6) + coff;
            unsigned o11 = ((unsigned)(r1 + cx1) << 6) + coff;

            union U { uint4 u; __half2 h2[4]; };
            U u00, u01, u10, u11;
            u00.u = *(const uint4*)(vb + o00);
            u01.u = *(const uint4*)(vb + o01);
            u10.u = *(const uint4*)(vb + o10);
            u11.u = *(const uint4*)(vb + o11);

            float wgt = wl[p];
            float w00 = (1.f - fx) * (1.f - fy) * wgt * vx0 * vy0;
            float w01 = fx * (1.f - fy) * wgt * vx1 * vy0;
            float w10 = (1.f - fx) * fy * wgt * vx0 * vy1;
            float w11 = fx * fy * wgt * vx1 * vy1;

#pragma unroll
            for (int j = 0; j < 4; ++j) {
                float2 f00 = __half22float2(u00.h2[j]);
                float2 f01 = __half22float2(u01.h2[j]);
                float2 f10 = __half22float2(u10.h2[j]);
                float2 f11 = __half22float2(u11.h2[j]);
                acc[j].x += w00 * f00.x + w01 * f01.x + w10 * f10.x + w11 * f11.x;
                acc[j].y += w00 * f00.y + w01 * f01.y + w10 * f10.y + w11 * f11.y;
            }
        }
    }

    float4* op = (float4*)out + bqh * (D / 4) + lane * 2;
    op[0] = make_float4(acc[0].x, acc[0].y, acc[1].x, acc[1].y);
    op[1] = make_float4(acc[2].x, acc[2].y, acc[3].x, acc[3].y);
}

// ---------------- fp32 fallback (round-4 kernel) ----------------
__global__ __launch_bounds__(256, 4) void msda_fwd_fp32_kernel(
    const float* __restrict__ value, const float* __restrict__ loc,
    const float* __restrict__ aw, float* __restrict__ out)
{
    constexpr int H = MSDA_H, D = MSDA_D, L = MSDA_L, P = MSDA_P;
    constexpr int S = MSDA_S, Q = MSDA_Q;
    const int lvl_sh[4]    = {7, 6, 5, 4};
    const int lvl_start[4] = {0, 16384, 20480, 21504};

    int i = blockIdx.x;
    int h = i & 7;
    int r = i >> 3;
    int b = r / MSDA_QBLK32;
    int qb = r - b * MSDA_QBLK32;

    int q = qb * 32 + (threadIdx.x >> 3);
    if (q >= Q) return;
    const unsigned coff = (threadIdx.x & 7) * 16;

    const size_t bqh = ((size_t)b * Q + q) * H + h;
    const float4* lp4 = (const float4*)(loc + bqh * (L * P * 2));
    const float4* wp4 = (const float4*)(aw  + bqh * (L * P));
    const char* vb = (const char*)(value + ((size_t)b * S * H + h) * D);

    float4 acc = {0.f, 0.f, 0.f, 0.f};

#pragma unroll
    for (int l = 0; l < L; ++l) {
        const int sh = lvl_sh[l];
        const int hw = 1 << sh;
        const float fhw = (float)hw;
        const int start = lvl_start[l];

        float4 la = lp4[2 * l + 0];
        float4 lb = lp4[2 * l + 1];
        float4 wv = wp4[l];
        float lx[4] = {la.x, la.z, lb.x, lb.z};
        float ly[4] = {la.y, la.w, lb.y, lb.w};
        float wl[4] = {wv.x, wv.y, wv.z, wv.w};

#pragma unroll
        for (int p = 0; p < P; ++p) {
            float x = lx[p] * fhw - 0.5f;
            float y = ly[p] * fhw - 0.5f;
            float xf = floorf(x), yf = floorf(y);
            float fx = x - xf, fy = y - yf;
            int x0 = (int)xf, y0 = (int)yf;
            int x1 = x0 + 1, y1 = y0 + 1;

            float vx0 = ((unsigned)x0 < (unsigned)hw) ? 1.f : 0.f;
            float vx1 = ((unsigned)x1 < (unsigned)hw) ? 1.f : 0.f;
            float vy0 = ((unsigned)y0 < (unsigned)hw) ? 1.f : 0.f;
            float vy1 = ((unsigned)y1 < (unsigned)hw) ? 1.f : 0.f;

            int cx0 = min(max(x0, 0), hw - 1);
            int cx1 = min(max(x1, 0), hw - 1);
            int cy0 = min(max(y0, 0), hw - 1);
            int cy1 = min(max(y1, 0), hw - 1);

            float wgt = wl[p];
            float w00 = (1.f - fx) * (1.f - fy) * wgt * vx0 * vy0;
            float w01 = fx * (1.f - fy) * wgt * vx1 * vy0;
            float w10 = (1.f - fx) * fy * wgt * vx0 * vy1;
            float w11 = fx * fy * wgt * vx1 * vy1;

            int r0 = start + (cy0 << sh);
            int r1 = start + (cy1 << sh);
            unsigned o00 = ((unsigned)(r0 + cx0) << 10) + coff;
            unsigned o01 = ((unsigned)(r0 + cx1) << 10) + coff;
            unsigned o10 = ((unsigned)(r1 + cx0) << 10) + coff;
            unsigned o11 = ((unsigned)(r1 + cx1) << 10) + coff;

            float4 v00 = *(const float4*)(vb + o00);
            float4 v01 = *(const float4*)(vb + o01);
            float4 v10 = *(const float4*)(vb + o10);
            float4 v11 = *(const float4*)(vb + o11);

            acc.x += w00 * v00.x + w01 * v01.x + w10 * v10.x + w11 * v11.x;
            acc.y += w00 * v00.y + w01 * v01.y + w10 * v10.y + w11 * v11.y;
            acc.z += w00 * v00.z + w01 * v01.z + w10 * v10.z + w11 * v11.z;
            acc.w += w00 * v00.w + w01 * v01.w + w10 * v10.w + w11 * v11.w;
        }
    }

    ((float4*)out)[bqh * (D / 4) + (threadIdx.x & 7)] = acc;
}

extern "C" void kernel_launch(void* const* d_in, const int* in_sizes, int n_in,
                              void* d_out, int out_size, void* d_ws, size_t ws_size,
                              hipStream_t stream) {
    const float* value = (const float*)d_in[0];
    const float* loc = (const float*)d_in[3];
    const float* aw  = (const float*)d_in[4];
    float* out = (float*)d_out;

    // one-time: allow 80KB dynamic LDS on the LDS-path kernel
    static int lds_ok = -1;
    if (lds_ok < 0) {
        hipError_t e = hipFuncSetAttribute(
            reinterpret_cast<const void*>(msda_fwd_lds_kernel),
            hipFuncAttributeMaxDynamicSharedMemorySize, MSDA_LDS_BYTES);
        lds_ok = (e == hipSuccess) ? 1 : 0;
    }

    const size_t need = (size_t)MSDA_B * MSDA_H * MSDA_S * MSDA_D * sizeof(__half);
    if (ws_size >= need) {
        __half* vw = (__half*)d_ws;
        msda_convert_kernel<<<(MSDA_B * MSDA_S * MSDA_H * MSDA_D / 4 + 255) / 256,
                              256, 0, stream>>>(value, vw);
        if (lds_ok) {
            const int grid = MSDA_B * MSDA_H * MSDA_NB;   // 512
            msda_fwd_lds_kernel<<<grid, 512, MSDA_LDS_BYTES, stream>>>(vw, loc, aw, out);
        } else {
            const int grid = 8 * MSDA_B * MSDA_QBLK16;    // 5024
            msda_fwd_fp16_kernel<<<grid, 256, 0, stream>>>(vw, loc, aw, out);
        }
    } else {
        const int grid = 8 * MSDA_B * MSDA_QBLK32;        // 10016
        msda_fwd_fp32_kernel<<<grid, 256, 0, stream>>>(value, loc, aw, out);
    }
}